// Round 1
// baseline (741.106 us; speedup 1.0000x reference)
//
#include <hip/hip_runtime.h>

// Problem constants (reference: N=8192, D=16)
#define NPTS 8192
#define DIM  16

constexpr int BLK = 256;          // threads per block
constexpr int IPT = 2;            // i's per thread
constexpr int TI  = BLK * IPT;    // 512 i per block
constexpr int NIB = NPTS / TI;    // 16 i-blocks
constexpr int JC  = 64;           // j-chunks (grid.y)
constexpr int TJ  = NPTS / JC;    // 128 j per chunk (one LDS tile)

// fit: sigma=1, l=1 -> k = exp(-d2/2);  mmd: sigma=1, l=2 -> k = exp(-d2/8)
#define FIT_SCALE (-0.5f)
#define MMD_SCALE (-0.125f)
#define REG_LAMBDA 0.01f

__device__ __forceinline__ float block_sum(float v, float* wbuf) {
#pragma unroll
  for (int o = 32; o > 0; o >>= 1) v += __shfl_down(v, o, 64);
  const int lane = threadIdx.x & 63;
  const int wid  = threadIdx.x >> 6;
  __syncthreads();
  if (lane == 0) wbuf[wid] = v;
  __syncthreads();
  float s = 0.f;
  if (threadIdx.x == 0) {
#pragma unroll
    for (int w = 0; w < BLK / 64; ++w) s += wbuf[w];
  }
  return s;
}

__global__ void k_sqnorm(const float* __restrict__ X, float* __restrict__ sq) {
  const int i = blockIdx.x * blockDim.x + threadIdx.x;
  const float4* xr = (const float4*)(X + (size_t)i * DIM);
  float s = 0.f;
#pragma unroll
  for (int q = 0; q < 4; ++q) {
    float4 v = xr[q];
    s += v.x * v.x + v.y * v.y + v.z * v.z + v.w * v.w;
  }
  sq[i] = s;
}

// Pass 1: U = fit_kXX @ Lam, accumulated across j-chunks via fp32 HW atomics.
__global__ __launch_bounds__(BLK, 2) void k_pass1(
    const float* __restrict__ X, const float* __restrict__ Lam,
    const float* __restrict__ sq, float* __restrict__ U) {
  __shared__ float sX[TJ * DIM];
  __shared__ float sL[TJ * DIM];
  __shared__ float ssq[TJ];

  const int j0 = blockIdx.y * TJ;
  for (int t = threadIdx.x; t < TJ * DIM / 4; t += BLK) {
    ((float4*)sX)[t] = ((const float4*)(X + (size_t)j0 * DIM))[t];
    ((float4*)sL)[t] = ((const float4*)(Lam + (size_t)j0 * DIM))[t];
  }
  if (threadIdx.x < TJ) ssq[threadIdx.x] = sq[j0 + threadIdx.x];
  __syncthreads();

  const int ibase = blockIdx.x * TI + threadIdx.x;
  float xi[IPT][DIM], sqi[IPT], acc[IPT][DIM];
#pragma unroll
  for (int p = 0; p < IPT; ++p) {
    const int i = ibase + p * BLK;
    const float4* xr = (const float4*)(X + (size_t)i * DIM);
#pragma unroll
    for (int q = 0; q < 4; ++q) {
      float4 v = xr[q];
      xi[p][4 * q + 0] = v.x; xi[p][4 * q + 1] = v.y;
      xi[p][4 * q + 2] = v.z; xi[p][4 * q + 3] = v.w;
    }
    sqi[p] = sq[i];
#pragma unroll
    for (int d = 0; d < DIM; ++d) acc[p][d] = 0.f;
  }

  for (int j = 0; j < TJ; ++j) {
    float xj[DIM], lj[DIM];
#pragma unroll
    for (int q = 0; q < 4; ++q) {
      float4 v = ((const float4*)(sX + j * DIM))[q];
      xj[4 * q + 0] = v.x; xj[4 * q + 1] = v.y; xj[4 * q + 2] = v.z; xj[4 * q + 3] = v.w;
      float4 l = ((const float4*)(sL + j * DIM))[q];
      lj[4 * q + 0] = l.x; lj[4 * q + 1] = l.y; lj[4 * q + 2] = l.z; lj[4 * q + 3] = l.w;
    }
    const float sj = ssq[j];
#pragma unroll
    for (int p = 0; p < IPT; ++p) {
      float t0 = xi[p][0] * xj[0], t1 = xi[p][1] * xj[1];
      float t2 = xi[p][2] * xj[2], t3 = xi[p][3] * xj[3];
#pragma unroll
      for (int d = 4; d < DIM; d += 4) {
        t0 = fmaf(xi[p][d + 0], xj[d + 0], t0);
        t1 = fmaf(xi[p][d + 1], xj[d + 1], t1);
        t2 = fmaf(xi[p][d + 2], xj[d + 2], t2);
        t3 = fmaf(xi[p][d + 3], xj[d + 3], t3);
      }
      const float dot = (t0 + t1) + (t2 + t3);
      float d2 = fmaxf(sqi[p] + sj - 2.f * dot, 0.f);
      const float k = __expf(FIT_SCALE * d2);
#pragma unroll
      for (int d = 0; d < DIM; ++d) acc[p][d] = fmaf(k, lj[d], acc[p][d]);
    }
  }

#pragma unroll
  for (int p = 0; p < IPT; ++p) {
    const int i = ibase + p * BLK;
#pragma unroll
    for (int d = 0; d < DIM; ++d) unsafeAtomicAdd(&U[(size_t)i * DIM + d], acc[p][d]);
  }
}

// Pass 2: loss_fit = sum_ij mmd_k(i,j) * (diff_i . diff_j), diff = U - Y.
// jc==0 blocks also accumulate reg = sum(Lam * U).
__global__ __launch_bounds__(BLK, 2) void k_pass2(
    const float* __restrict__ X, const float* __restrict__ Y,
    const float* __restrict__ Lam, const float* __restrict__ sq,
    const float* __restrict__ U, float* __restrict__ accums) {
  __shared__ float sX[TJ * DIM];
  __shared__ float sDf[TJ * DIM];
  __shared__ float ssq[TJ];
  __shared__ float wred[BLK / 64];

  const int j0 = blockIdx.y * TJ;
  for (int t = threadIdx.x; t < TJ * DIM / 4; t += BLK) {
    ((float4*)sX)[t] = ((const float4*)(X + (size_t)j0 * DIM))[t];
    float4 u = ((const float4*)(U + (size_t)j0 * DIM))[t];
    float4 y = ((const float4*)(Y + (size_t)j0 * DIM))[t];
    ((float4*)sDf)[t] = make_float4(u.x - y.x, u.y - y.y, u.z - y.z, u.w - y.w);
  }
  if (threadIdx.x < TJ) ssq[threadIdx.x] = sq[j0 + threadIdx.x];
  __syncthreads();

  const int ibase = blockIdx.x * TI + threadIdx.x;
  float xi[IPT][DIM], di[IPT][DIM], sqi[IPT];
  float regp = 0.f;
#pragma unroll
  for (int p = 0; p < IPT; ++p) {
    const int i = ibase + p * BLK;
    const float4* xr = (const float4*)(X + (size_t)i * DIM);
    const float4* ur = (const float4*)(U + (size_t)i * DIM);
    const float4* yr = (const float4*)(Y + (size_t)i * DIM);
#pragma unroll
    for (int q = 0; q < 4; ++q) {
      float4 v = xr[q];
      xi[p][4 * q + 0] = v.x; xi[p][4 * q + 1] = v.y;
      xi[p][4 * q + 2] = v.z; xi[p][4 * q + 3] = v.w;
      float4 u = ur[q];
      float4 y = yr[q];
      di[p][4 * q + 0] = u.x - y.x; di[p][4 * q + 1] = u.y - y.y;
      di[p][4 * q + 2] = u.z - y.z; di[p][4 * q + 3] = u.w - y.w;
      if (blockIdx.y == 0) {
        float4 l = ((const float4*)(Lam + (size_t)i * DIM))[q];
        regp += l.x * u.x + l.y * u.y + l.z * u.z + l.w * u.w;
      }
    }
    sqi[p] = sq[i];
  }

  float s = 0.f;
  for (int j = 0; j < TJ; ++j) {
    float xj[DIM], dfj[DIM];
#pragma unroll
    for (int q = 0; q < 4; ++q) {
      float4 v = ((const float4*)(sX + j * DIM))[q];
      xj[4 * q + 0] = v.x; xj[4 * q + 1] = v.y; xj[4 * q + 2] = v.z; xj[4 * q + 3] = v.w;
      float4 f = ((const float4*)(sDf + j * DIM))[q];
      dfj[4 * q + 0] = f.x; dfj[4 * q + 1] = f.y; dfj[4 * q + 2] = f.z; dfj[4 * q + 3] = f.w;
    }
    const float sj = ssq[j];
#pragma unroll
    for (int p = 0; p < IPT; ++p) {
      float t0 = xi[p][0] * xj[0], t1 = xi[p][1] * xj[1];
      float t2 = xi[p][2] * xj[2], t3 = xi[p][3] * xj[3];
      float u0 = di[p][0] * dfj[0], u1 = di[p][1] * dfj[1];
      float u2 = di[p][2] * dfj[2], u3 = di[p][3] * dfj[3];
#pragma unroll
      for (int d = 4; d < DIM; d += 4) {
        t0 = fmaf(xi[p][d + 0], xj[d + 0], t0);
        t1 = fmaf(xi[p][d + 1], xj[d + 1], t1);
        t2 = fmaf(xi[p][d + 2], xj[d + 2], t2);
        t3 = fmaf(xi[p][d + 3], xj[d + 3], t3);
        u0 = fmaf(di[p][d + 0], dfj[d + 0], u0);
        u1 = fmaf(di[p][d + 1], dfj[d + 1], u1);
        u2 = fmaf(di[p][d + 2], dfj[d + 2], u2);
        u3 = fmaf(di[p][d + 3], dfj[d + 3], u3);
      }
      const float dot  = (t0 + t1) + (t2 + t3);
      const float dotd = (u0 + u1) + (u2 + u3);
      float d2 = fmaxf(sqi[p] + sj - 2.f * dot, 0.f);
      const float k = __expf(MMD_SCALE * d2);
      s = fmaf(k, dotd, s);
    }
  }

  const float stot = block_sum(s, wred);
  if (threadIdx.x == 0) unsafeAtomicAdd(&accums[0], stot);
  if (blockIdx.y == 0) {
    __syncthreads();
    const float rtot = block_sum(regp, wred);
    if (threadIdx.x == 0) unsafeAtomicAdd(&accums[1], rtot);
  }
}

__global__ void k_final(const float* __restrict__ accums, float* __restrict__ out) {
  out[0] = accums[0] + REG_LAMBDA * accums[1];
}

extern "C" void kernel_launch(void* const* d_in, const int* in_sizes, int n_in,
                              void* d_out, int out_size, void* d_ws, size_t ws_size,
                              hipStream_t stream) {
  const float* X   = (const float*)d_in[0];
  const float* Y   = (const float*)d_in[1];
  const float* Lam = (const float*)d_in[2];
  float* out = (float*)d_out;

  // ws layout: sq [NPTS] | U [NPTS*DIM] | accums [2]
  float* sq     = (float*)d_ws;
  float* U      = sq + NPTS;
  float* accums = U + (size_t)NPTS * DIM;

  // Zero U and accums (ws is poisoned 0xAA before every call).
  hipMemsetAsync(U, 0, ((size_t)NPTS * DIM + 2) * sizeof(float), stream);

  k_sqnorm<<<NPTS / BLK, BLK, 0, stream>>>(X, sq);
  k_pass1<<<dim3(NIB, JC), BLK, 0, stream>>>(X, Lam, sq, U);
  k_pass2<<<dim3(NIB, JC), BLK, 0, stream>>>(X, Y, Lam, sq, U, accums);
  k_final<<<1, 1, 0, stream>>>(accums, out);
}

// Round 2
// 671.723 us; speedup vs baseline: 1.1033x; 1.1033x over previous
//
#include <hip/hip_runtime.h>

// Problem: N=8192, D=16 RBF transport loss.
#define NPTS 8192
#define DIM  16

constexpr int BLK = 256;          // threads per block, 1 i per thread
constexpr int NIB = NPTS / BLK;   // 32 i-blocks
constexpr int JC  = 64;           // j-chunks (grid.y)
constexpr int TJ  = NPTS / JC;    // 128 j per chunk (LDS tile)

// fit: sigma=1, l=1 -> k = exp(-d2/2);  mmd: sigma=1, l=2 -> k = exp(-d2/8)
#define FIT_SCALE (-0.5f)
#define MMD_SCALE (-0.125f)
#define REG_LAMBDA 0.01f

__device__ __forceinline__ float dot4(float4 a, float4 b) {
  return fmaf(a.x, b.x, fmaf(a.y, b.y, fmaf(a.z, b.z, a.w * b.w)));
}

__device__ __forceinline__ void fma4(float4& a, float k, float4 b) {
  a.x = fmaf(k, b.x, a.x);
  a.y = fmaf(k, b.y, a.y);
  a.z = fmaf(k, b.z, a.z);
  a.w = fmaf(k, b.w, a.w);
}

__device__ __forceinline__ float block_sum(float v, float* wbuf) {
#pragma unroll
  for (int o = 32; o > 0; o >>= 1) v += __shfl_down(v, o, 64);
  const int lane = threadIdx.x & 63;
  const int wid  = threadIdx.x >> 6;
  __syncthreads();
  if (lane == 0) wbuf[wid] = v;
  __syncthreads();
  float s = 0.f;
  if (threadIdx.x == 0) {
#pragma unroll
    for (int w = 0; w < BLK / 64; ++w) s += wbuf[w];
  }
  return s;
}

__global__ void k_sqnorm(const float4* __restrict__ Xv, float* __restrict__ sq) {
  const int i = blockIdx.x * blockDim.x + threadIdx.x;
  float4 a = Xv[(size_t)i * 4 + 0];
  float4 b = Xv[(size_t)i * 4 + 1];
  float4 c = Xv[(size_t)i * 4 + 2];
  float4 d = Xv[(size_t)i * 4 + 3];
  sq[i] = dot4(a, a) + dot4(b, b) + dot4(c, c) + dot4(d, d);
}

// Pass 1: U = fit_kXX @ Lam, j-chunked, fp32 HW atomics into U.
// All per-thread state in named float4 registers (no arrays -> no scratch spill).
__global__ __launch_bounds__(BLK) void k_pass1(
    const float4* __restrict__ Xv, const float4* __restrict__ Lv,
    const float* __restrict__ sq, float* __restrict__ U) {
  __shared__ float4 sX[TJ * 4];
  __shared__ float4 sL[TJ * 4];
  __shared__ float  ssq[TJ];

  const int j0 = blockIdx.y * TJ;
  for (int t = threadIdx.x; t < TJ * 4; t += BLK) {
    sX[t] = Xv[(size_t)j0 * 4 + t];
    sL[t] = Lv[(size_t)j0 * 4 + t];
  }
  if (threadIdx.x < TJ) ssq[threadIdx.x] = sq[j0 + threadIdx.x];
  __syncthreads();

  const int i = blockIdx.x * BLK + threadIdx.x;
  const float4 xi0 = Xv[(size_t)i * 4 + 0];
  const float4 xi1 = Xv[(size_t)i * 4 + 1];
  const float4 xi2 = Xv[(size_t)i * 4 + 2];
  const float4 xi3 = Xv[(size_t)i * 4 + 3];
  const float  sqi = sq[i];
  float4 a0 = {0.f, 0.f, 0.f, 0.f}, a1 = a0, a2 = a0, a3 = a0;

#pragma unroll 2
  for (int j = 0; j < TJ; ++j) {
    const float4 xj0 = sX[j * 4 + 0];
    const float4 xj1 = sX[j * 4 + 1];
    const float4 xj2 = sX[j * 4 + 2];
    const float4 xj3 = sX[j * 4 + 3];
    const float  sj  = ssq[j];
    const float dot = (dot4(xi0, xj0) + dot4(xi1, xj1)) +
                      (dot4(xi2, xj2) + dot4(xi3, xj3));
    const float d2 = fmaxf(sqi + sj - 2.f * dot, 0.f);
    const float k  = __expf(FIT_SCALE * d2);
    const float4 l0 = sL[j * 4 + 0];
    const float4 l1 = sL[j * 4 + 1];
    const float4 l2 = sL[j * 4 + 2];
    const float4 l3 = sL[j * 4 + 3];
    fma4(a0, k, l0);
    fma4(a1, k, l1);
    fma4(a2, k, l2);
    fma4(a3, k, l3);
  }

  float* Ui = U + (size_t)i * DIM;
  unsafeAtomicAdd(Ui + 0,  a0.x); unsafeAtomicAdd(Ui + 1,  a0.y);
  unsafeAtomicAdd(Ui + 2,  a0.z); unsafeAtomicAdd(Ui + 3,  a0.w);
  unsafeAtomicAdd(Ui + 4,  a1.x); unsafeAtomicAdd(Ui + 5,  a1.y);
  unsafeAtomicAdd(Ui + 6,  a1.z); unsafeAtomicAdd(Ui + 7,  a1.w);
  unsafeAtomicAdd(Ui + 8,  a2.x); unsafeAtomicAdd(Ui + 9,  a2.y);
  unsafeAtomicAdd(Ui + 10, a2.z); unsafeAtomicAdd(Ui + 11, a2.w);
  unsafeAtomicAdd(Ui + 12, a3.x); unsafeAtomicAdd(Ui + 13, a3.y);
  unsafeAtomicAdd(Ui + 14, a3.z); unsafeAtomicAdd(Ui + 15, a3.w);
}

// Pass 2: loss_fit = sum_ij mmd_k(i,j) * (diff_i . diff_j), diff = U - Y.
// blockIdx.y==0 blocks also accumulate reg = sum(Lam * U).
__global__ __launch_bounds__(BLK) void k_pass2(
    const float4* __restrict__ Xv, const float4* __restrict__ Yv,
    const float4* __restrict__ Lv, const float* __restrict__ sq,
    const float4* __restrict__ Uv, float* __restrict__ accums) {
  __shared__ float4 sX[TJ * 4];
  __shared__ float4 sDf[TJ * 4];
  __shared__ float  ssq[TJ];
  __shared__ float  wred[BLK / 64];

  const int j0 = blockIdx.y * TJ;
  for (int t = threadIdx.x; t < TJ * 4; t += BLK) {
    sX[t] = Xv[(size_t)j0 * 4 + t];
    const float4 u = Uv[(size_t)j0 * 4 + t];
    const float4 y = Yv[(size_t)j0 * 4 + t];
    sDf[t] = make_float4(u.x - y.x, u.y - y.y, u.z - y.z, u.w - y.w);
  }
  if (threadIdx.x < TJ) ssq[threadIdx.x] = sq[j0 + threadIdx.x];
  __syncthreads();

  const int i = blockIdx.x * BLK + threadIdx.x;
  const float4 xi0 = Xv[(size_t)i * 4 + 0];
  const float4 xi1 = Xv[(size_t)i * 4 + 1];
  const float4 xi2 = Xv[(size_t)i * 4 + 2];
  const float4 xi3 = Xv[(size_t)i * 4 + 3];
  const float  sqi = sq[i];

  const float4 u0 = Uv[(size_t)i * 4 + 0];
  const float4 u1 = Uv[(size_t)i * 4 + 1];
  const float4 u2 = Uv[(size_t)i * 4 + 2];
  const float4 u3 = Uv[(size_t)i * 4 + 3];
  const float4 y0 = Yv[(size_t)i * 4 + 0];
  const float4 y1 = Yv[(size_t)i * 4 + 1];
  const float4 y2 = Yv[(size_t)i * 4 + 2];
  const float4 y3 = Yv[(size_t)i * 4 + 3];
  const float4 di0 = make_float4(u0.x - y0.x, u0.y - y0.y, u0.z - y0.z, u0.w - y0.w);
  const float4 di1 = make_float4(u1.x - y1.x, u1.y - y1.y, u1.z - y1.z, u1.w - y1.w);
  const float4 di2 = make_float4(u2.x - y2.x, u2.y - y2.y, u2.z - y2.z, u2.w - y2.w);
  const float4 di3 = make_float4(u3.x - y3.x, u3.y - y3.y, u3.z - y3.z, u3.w - y3.w);

  float regp = 0.f;
  if (blockIdx.y == 0) {
    const float4 l0 = Lv[(size_t)i * 4 + 0];
    const float4 l1 = Lv[(size_t)i * 4 + 1];
    const float4 l2 = Lv[(size_t)i * 4 + 2];
    const float4 l3 = Lv[(size_t)i * 4 + 3];
    regp = (dot4(l0, u0) + dot4(l1, u1)) + (dot4(l2, u2) + dot4(l3, u3));
  }

  float s = 0.f;
#pragma unroll 2
  for (int j = 0; j < TJ; ++j) {
    const float4 xj0 = sX[j * 4 + 0];
    const float4 xj1 = sX[j * 4 + 1];
    const float4 xj2 = sX[j * 4 + 2];
    const float4 xj3 = sX[j * 4 + 3];
    const float  sj  = ssq[j];
    const float4 f0 = sDf[j * 4 + 0];
    const float4 f1 = sDf[j * 4 + 1];
    const float4 f2 = sDf[j * 4 + 2];
    const float4 f3 = sDf[j * 4 + 3];
    const float dot = (dot4(xi0, xj0) + dot4(xi1, xj1)) +
                      (dot4(xi2, xj2) + dot4(xi3, xj3));
    const float dotd = (dot4(di0, f0) + dot4(di1, f1)) +
                       (dot4(di2, f2) + dot4(di3, f3));
    const float d2 = fmaxf(sqi + sj - 2.f * dot, 0.f);
    const float k  = __expf(MMD_SCALE * d2);
    s = fmaf(k, dotd, s);
  }

  const float stot = block_sum(s, wred);
  if (threadIdx.x == 0) unsafeAtomicAdd(&accums[0], stot);
  if (blockIdx.y == 0) {
    __syncthreads();
    const float rtot = block_sum(regp, wred);
    if (threadIdx.x == 0) unsafeAtomicAdd(&accums[1], rtot);
  }
}

__global__ void k_final(const float* __restrict__ accums, float* __restrict__ out) {
  out[0] = accums[0] + REG_LAMBDA * accums[1];
}

extern "C" void kernel_launch(void* const* d_in, const int* in_sizes, int n_in,
                              void* d_out, int out_size, void* d_ws, size_t ws_size,
                              hipStream_t stream) {
  const float4* Xv = (const float4*)d_in[0];
  const float4* Yv = (const float4*)d_in[1];
  const float4* Lv = (const float4*)d_in[2];
  float* out = (float*)d_out;

  // ws layout: sq [NPTS] | U [NPTS*DIM] | accums [2]
  float* sq     = (float*)d_ws;
  float* U      = sq + NPTS;
  float* accums = U + (size_t)NPTS * DIM;

  hipMemsetAsync(U, 0, ((size_t)NPTS * DIM + 2) * sizeof(float), stream);

  k_sqnorm<<<NPTS / BLK, BLK, 0, stream>>>(Xv, sq);
  k_pass1<<<dim3(NIB, JC), BLK, 0, stream>>>(Xv, Lv, sq, U);
  k_pass2<<<dim3(NIB, JC), BLK, 0, stream>>>(Xv, Yv, Lv, sq, (const float4*)U, accums);
  k_final<<<1, 1, 0, stream>>>(accums, out);
}

// Round 4
// 292.707 us; speedup vs baseline: 2.5319x; 2.2949x over previous
//
#include <hip/hip_runtime.h>

// Problem: N=8192, D=16 RBF transport loss.
#define NPTS 8192
#define DIM  16

constexpr int BLK = 256;          // threads per block, 1 i per thread
constexpr int NIB = NPTS / BLK;   // 32 i-blocks

// fit: sigma=1, l=1 -> k = exp(-d2/2);  mmd: sigma=1, l=2 -> k = exp(-d2/8)
#define FIT_SCALE (-0.5f)
#define MMD_SCALE (-0.125f)
#define REG_LAMBDA 0.01f

// Uniform (wave-scalar) load via constant address space. Scalar float only:
// trivially copyable across address spaces (HIP_vector_type ctors are not).
// Adjacent s_load_dwords get merged to s_load_dwordx4 by the backend.
__device__ __forceinline__ float uloadf(const float* p) {
#if defined(__HIP_DEVICE_COMPILE__)
  return *(__attribute__((address_space(4))) const float*)p;
#else
  return *p;
#endif
}

__device__ __forceinline__ float4 uload4(const float4* p) {
  const float* f = (const float*)p;
  return make_float4(uloadf(f + 0), uloadf(f + 1), uloadf(f + 2), uloadf(f + 3));
}

__device__ __forceinline__ float dot4(float4 a, float4 b) {
  return fmaf(a.x, b.x, fmaf(a.y, b.y, fmaf(a.z, b.z, a.w * b.w)));
}

__device__ __forceinline__ void fma4(float4& a, float k, float4 b) {
  a.x = fmaf(k, b.x, a.x);
  a.y = fmaf(k, b.y, a.y);
  a.z = fmaf(k, b.z, a.z);
  a.w = fmaf(k, b.w, a.w);
}

__device__ __forceinline__ void add4(float4& a, float4 b) {
  a.x += b.x; a.y += b.y; a.z += b.z; a.w += b.w;
}

__device__ __forceinline__ float block_sum(float v, float* wbuf) {
#pragma unroll
  for (int o = 32; o > 0; o >>= 1) v += __shfl_down(v, o, 64);
  const int lane = threadIdx.x & 63;
  const int wid  = threadIdx.x >> 6;
  __syncthreads();
  if (lane == 0) wbuf[wid] = v;
  __syncthreads();
  float s = 0.f;
  if (threadIdx.x == 0) {
#pragma unroll
    for (int w = 0; w < BLK / 64; ++w) s += wbuf[w];
  }
  return s;
}

__global__ void k_sqnorm(const float4* __restrict__ Xv, float* __restrict__ sq) {
  const int i = blockIdx.x * blockDim.x + threadIdx.x;
  float4 a = Xv[(size_t)i * 4 + 0];
  float4 b = Xv[(size_t)i * 4 + 1];
  float4 c = Xv[(size_t)i * 4 + 2];
  float4 d = Xv[(size_t)i * 4 + 3];
  sq[i] = dot4(a, a) + dot4(b, b) + dot4(c, c) + dot4(d, d);
}

// Pass 1: partial U = fit_kXX @ Lam over this block's j-span.
// j-tile data via scalar (SGPR) loads; plain coalesced stores to Upart.
__global__ __launch_bounds__(BLK) void k_pass1(
    const float4* __restrict__ Xv, const float4* __restrict__ Lv,
    const float* __restrict__ sq, float4* __restrict__ Upart, int span) {
  const int i = blockIdx.x * BLK + threadIdx.x;
  const float4 xi0 = Xv[(size_t)i * 4 + 0];
  const float4 xi1 = Xv[(size_t)i * 4 + 1];
  const float4 xi2 = Xv[(size_t)i * 4 + 2];
  const float4 xi3 = Xv[(size_t)i * 4 + 3];
  const float  sqi = sq[i];
  float4 a0 = {0.f, 0.f, 0.f, 0.f}, a1 = a0, a2 = a0, a3 = a0;

  const int jbeg = blockIdx.y * span;
  const int jend = jbeg + span;
#pragma unroll 2
  for (int j = jbeg; j < jend; ++j) {
    const float4 xj0 = uload4(Xv + (size_t)j * 4 + 0);
    const float4 xj1 = uload4(Xv + (size_t)j * 4 + 1);
    const float4 xj2 = uload4(Xv + (size_t)j * 4 + 2);
    const float4 xj3 = uload4(Xv + (size_t)j * 4 + 3);
    const float  sqj = uloadf(sq + j);
    const float dot = (dot4(xi0, xj0) + dot4(xi1, xj1)) +
                      (dot4(xi2, xj2) + dot4(xi3, xj3));
    const float d2 = fmaxf(fmaf(-2.f, dot, sqi + sqj), 0.f);
    const float k  = __expf(FIT_SCALE * d2);
    const float4 l0 = uload4(Lv + (size_t)j * 4 + 0);
    const float4 l1 = uload4(Lv + (size_t)j * 4 + 1);
    const float4 l2 = uload4(Lv + (size_t)j * 4 + 2);
    const float4 l3 = uload4(Lv + (size_t)j * 4 + 3);
    fma4(a0, k, l0);
    fma4(a1, k, l1);
    fma4(a2, k, l2);
    fma4(a3, k, l3);
  }

  float4* dst = Upart + ((size_t)blockIdx.y * NPTS + i) * 4;
  dst[0] = a0; dst[1] = a1; dst[2] = a2; dst[3] = a3;
}

// Reduce partials -> diff = U - Y; fold reg = sum(Lam * U) into accums[1].
__global__ __launch_bounds__(BLK) void k_reduce(
    const float4* __restrict__ Upart, const float4* __restrict__ Yv,
    const float4* __restrict__ Lv, float4* __restrict__ diffv,
    float* __restrict__ accums, int jc) {
  __shared__ float wred[BLK / 64];
  const int i = blockIdx.x * BLK + threadIdx.x;
  float4 u0 = {0.f, 0.f, 0.f, 0.f}, u1 = u0, u2 = u0, u3 = u0;
  for (int c = 0; c < jc; ++c) {
    const float4* p = Upart + ((size_t)c * NPTS + i) * 4;
    add4(u0, p[0]); add4(u1, p[1]); add4(u2, p[2]); add4(u3, p[3]);
  }
  const float4 y0 = Yv[(size_t)i * 4 + 0];
  const float4 y1 = Yv[(size_t)i * 4 + 1];
  const float4 y2 = Yv[(size_t)i * 4 + 2];
  const float4 y3 = Yv[(size_t)i * 4 + 3];
  float4* dst = diffv + (size_t)i * 4;
  dst[0] = make_float4(u0.x - y0.x, u0.y - y0.y, u0.z - y0.z, u0.w - y0.w);
  dst[1] = make_float4(u1.x - y1.x, u1.y - y1.y, u1.z - y1.z, u1.w - y1.w);
  dst[2] = make_float4(u2.x - y2.x, u2.y - y2.y, u2.z - y2.z, u2.w - y2.w);
  dst[3] = make_float4(u3.x - y3.x, u3.y - y3.y, u3.z - y3.z, u3.w - y3.w);

  const float4 l0 = Lv[(size_t)i * 4 + 0];
  const float4 l1 = Lv[(size_t)i * 4 + 1];
  const float4 l2 = Lv[(size_t)i * 4 + 2];
  const float4 l3 = Lv[(size_t)i * 4 + 3];
  const float regp = (dot4(l0, u0) + dot4(l1, u1)) + (dot4(l2, u2) + dot4(l3, u3));
  const float rtot = block_sum(regp, wred);
  if (threadIdx.x == 0) unsafeAtomicAdd(&accums[1], rtot);
}

// Pass 2: loss_fit = sum_ij mmd_k(i,j) * (diff_i . diff_j).
__global__ __launch_bounds__(BLK) void k_pass2(
    const float4* __restrict__ Xv, const float4* __restrict__ diffv,
    const float* __restrict__ sq, float* __restrict__ accums, int span) {
  __shared__ float wred[BLK / 64];
  const int i = blockIdx.x * BLK + threadIdx.x;
  const float4 xi0 = Xv[(size_t)i * 4 + 0];
  const float4 xi1 = Xv[(size_t)i * 4 + 1];
  const float4 xi2 = Xv[(size_t)i * 4 + 2];
  const float4 xi3 = Xv[(size_t)i * 4 + 3];
  const float  sqi = sq[i];
  const float4 di0 = diffv[(size_t)i * 4 + 0];
  const float4 di1 = diffv[(size_t)i * 4 + 1];
  const float4 di2 = diffv[(size_t)i * 4 + 2];
  const float4 di3 = diffv[(size_t)i * 4 + 3];

  float s = 0.f;
  const int jbeg = blockIdx.y * span;
  const int jend = jbeg + span;
#pragma unroll 2
  for (int j = jbeg; j < jend; ++j) {
    const float4 xj0 = uload4(Xv + (size_t)j * 4 + 0);
    const float4 xj1 = uload4(Xv + (size_t)j * 4 + 1);
    const float4 xj2 = uload4(Xv + (size_t)j * 4 + 2);
    const float4 xj3 = uload4(Xv + (size_t)j * 4 + 3);
    const float  sqj = uloadf(sq + j);
    const float4 f0 = uload4(diffv + (size_t)j * 4 + 0);
    const float4 f1 = uload4(diffv + (size_t)j * 4 + 1);
    const float4 f2 = uload4(diffv + (size_t)j * 4 + 2);
    const float4 f3 = uload4(diffv + (size_t)j * 4 + 3);
    const float dot = (dot4(xi0, xj0) + dot4(xi1, xj1)) +
                      (dot4(xi2, xj2) + dot4(xi3, xj3));
    const float dotd = (dot4(di0, f0) + dot4(di1, f1)) +
                       (dot4(di2, f2) + dot4(di3, f3));
    const float d2 = fmaxf(fmaf(-2.f, dot, sqi + sqj), 0.f);
    const float k  = __expf(MMD_SCALE * d2);
    s = fmaf(k, dotd, s);
  }

  const float stot = block_sum(s, wred);
  if (threadIdx.x == 0) unsafeAtomicAdd(&accums[0], stot);
}

__global__ void k_final(const float* __restrict__ accums, float* __restrict__ out) {
  out[0] = accums[0] + REG_LAMBDA * accums[1];
}

extern "C" void kernel_launch(void* const* d_in, const int* in_sizes, int n_in,
                              void* d_out, int out_size, void* d_ws, size_t ws_size,
                              hipStream_t stream) {
  const float4* Xv = (const float4*)d_in[0];
  const float4* Yv = (const float4*)d_in[1];
  const float4* Lv = (const float4*)d_in[2];
  float* out = (float*)d_out;

  // ws layout (floats): sq [8192] | diff [8192*16] | accums [16 pad] | Upart [jc*8192*16]
  float*  sq     = (float*)d_ws;
  float4* diffv  = (float4*)(sq + NPTS);
  float*  accums = sq + NPTS + (size_t)NPTS * DIM;
  float4* Upart  = (float4*)(accums + 16);

  // Pick pass-1 chunk count to fit ws; deterministic (ws_size fixed per session).
  int jc = 32;
  while (jc > 2 &&
         ((size_t)NPTS + (size_t)NPTS * DIM + 16 + (size_t)jc * NPTS * DIM) * 4 > ws_size)
    jc >>= 1;
  const int span1 = NPTS / jc;
  const int jc2 = 32, span2 = NPTS / jc2;

  hipMemsetAsync(accums, 0, 2 * sizeof(float), stream);
  k_sqnorm<<<NIB, BLK, 0, stream>>>(Xv, sq);
  k_pass1<<<dim3(NIB, jc), BLK, 0, stream>>>(Xv, Lv, sq, Upart, span1);
  k_reduce<<<NIB, BLK, 0, stream>>>(Upart, Yv, Lv, diffv, accums, jc);
  k_pass2<<<dim3(NIB, jc2), BLK, 0, stream>>>(Xv, diffv, sq, accums, span2);
  k_final<<<1, 1, 0, stream>>>(accums, out);
}

// Round 5
// 135.304 us; speedup vs baseline: 5.4774x; 2.1633x over previous
//
#include <hip/hip_runtime.h>

// Problem: N=8192, D=16 RBF transport loss — MFMA fp16 formulation.
#define NPTS 8192
#define DIM  16

constexpr int BLK = 256;
constexpr int NIB = NPTS / BLK;   // 32

#define REG_LAMBDA 0.01f

typedef _Float16 h8 __attribute__((ext_vector_type(8)));
typedef float    f4 __attribute__((ext_vector_type(4)));

__device__ __forceinline__ float dot4(float4 a, float4 b) {
  return fmaf(a.x, b.x, fmaf(a.y, b.y, fmaf(a.z, b.z, a.w * b.w)));
}
__device__ __forceinline__ void add4(float4& a, float4 b) {
  a.x += b.x; a.y += b.y; a.z += b.z; a.w += b.w;
}

__device__ __forceinline__ float block_sum(float v, float* wbuf) {
#pragma unroll
  for (int o = 32; o > 0; o >>= 1) v += __shfl_down(v, o, 64);
  const int lane = threadIdx.x & 63;
  const int wid  = threadIdx.x >> 6;
  __syncthreads();
  if (lane == 0) wbuf[wid] = v;
  __syncthreads();
  float s = 0.f;
  if (threadIdx.x == 0) {
#pragma unroll
    for (int w = 0; w < BLK / 64; ++w) s += wbuf[w];
  }
  return s;
}

// Prep: X -> fp16 Xh (row-major), Lam -> fp16 LamT (transposed 16 x N),
// sqnorms from the ROUNDED X (consistent with MFMA dots), pre-scaled.
__global__ __launch_bounds__(BLK) void k_prep(
    const float4* __restrict__ Xv, const float4* __restrict__ Lv,
    _Float16* __restrict__ Xh, _Float16* __restrict__ LamT,
    float* __restrict__ csq1, float* __restrict__ csq2) {
  const int i = blockIdx.x * BLK + threadIdx.x;
  float sqsum = 0.f;
  _Float16* xr = Xh + (size_t)i * DIM;
#pragma unroll
  for (int q = 0; q < 4; ++q) {
    const float4 v = Xv[(size_t)i * 4 + q];
    const _Float16 h0 = (_Float16)v.x, h1 = (_Float16)v.y;
    const _Float16 h2 = (_Float16)v.z, h3 = (_Float16)v.w;
    xr[4 * q + 0] = h0; xr[4 * q + 1] = h1;
    xr[4 * q + 2] = h2; xr[4 * q + 3] = h3;
    const float f0 = (float)h0, f1 = (float)h1, f2 = (float)h2, f3 = (float)h3;
    sqsum += f0 * f0 + f1 * f1 + f2 * f2 + f3 * f3;
    const float4 l = Lv[(size_t)i * 4 + q];
    LamT[(size_t)(4 * q + 0) * NPTS + i] = (_Float16)l.x;
    LamT[(size_t)(4 * q + 1) * NPTS + i] = (_Float16)l.y;
    LamT[(size_t)(4 * q + 2) * NPTS + i] = (_Float16)l.z;
    LamT[(size_t)(4 * q + 3) * NPTS + i] = (_Float16)l.w;
  }
  csq1[i] = -0.5f   * sqsum;  // fit:  arg = csq1i + csq1j + dot
  csq2[i] = -0.125f * sqsum;  // mmd:  arg = 0.25*dot + csq2i + csq2j
}

// Pass 1: U_tile += exp(fit) @ Lam via MFMA1 -> exp -> LDS transpose -> MFMA2.
// Fragment maps (guide §3, m89/m120 verified):
//   A[m=lane&15][k=(lane>>4)*8+j], B[k=(lane>>4)*8+j][n=lane&15],
//   C/D: col=lane&15, row=(lane>>4)*4+reg.
__global__ __launch_bounds__(BLK) void k_pass1(
    const _Float16* __restrict__ Xh, const _Float16* __restrict__ LamT,
    const float* __restrict__ csq1, float* __restrict__ Upart, int span) {
  __shared__ __align__(16) _Float16 sP[4][16][32];  // per-wave P tile, cols 16..31 zero
  const int lane = threadIdx.x & 63;
  const int w    = threadIdx.x >> 6;
  const int l16  = lane & 15;
  const int quad = lane >> 4;
  const h8 hz = (h8)(_Float16)0.f;

  // zero this wave's LDS region once (wave-coherent; DS pipe is in-order per wave)
  ((h8*)&sP[w][0][0])[lane] = hz;

  const int i0 = blockIdx.x * 64 + w * 16;
  h8 ax = hz;
  if (quad < 2) ax = *(const h8*)(Xh + (size_t)(i0 + l16) * DIM + quad * 8);
  const int ir = i0 + quad * 4;
  f4 ci;
  ci[0] = csq1[ir + 0]; ci[1] = csq1[ir + 1];
  ci[2] = csq1[ir + 2]; ci[3] = csq1[ir + 3];

  f4 U = (f4)0.f;
  const int jbeg = blockIdx.y * span;
  const int jend = jbeg + span;
#pragma unroll 2
  for (int j0 = jbeg; j0 < jend; j0 += 16) {
    h8 bx = hz;
    if (quad < 2) bx = *(const h8*)(Xh + (size_t)(j0 + l16) * DIM + quad * 8);
    const float cj = csq1[j0 + l16];
    const f4 dot = __builtin_amdgcn_mfma_f32_16x16x32_f16(ax, bx, (f4)0.f, 0, 0, 0);
#pragma unroll
    for (int r = 0; r < 4; ++r) {
      const float p = __expf(dot[r] + ci[r] + cj);
      sP[w][quad * 4 + r][l16] = (_Float16)p;   // C-layout -> row-major P
    }
    const h8 ap = *(const h8*)&sP[w][l16][quad * 8];  // A-layout read (pad zeros)
    const h8 bl = *(const h8*)(LamT + (size_t)l16 * NPTS + j0 + quad * 8);
    U = __builtin_amdgcn_mfma_f32_16x16x32_f16(ap, bl, U, 0, 0, 0);
  }

  float* dst = Upart + ((size_t)blockIdx.y * NPTS + i0) * DIM;
#pragma unroll
  for (int r = 0; r < 4; ++r)
    dst[(quad * 4 + r) * DIM + l16] = U[r];
}

// Reduce partials -> U fp32; diff = U - Y -> fp16 Dh; reg = sum(Lam*U).
__global__ __launch_bounds__(BLK) void k_reduce(
    const float4* __restrict__ Upart, const float4* __restrict__ Yv,
    const float4* __restrict__ Lv, _Float16* __restrict__ Dh,
    float* __restrict__ accums, int jc) {
  __shared__ float wred[BLK / 64];
  const int i = blockIdx.x * BLK + threadIdx.x;
  float4 u0 = {0.f, 0.f, 0.f, 0.f}, u1 = u0, u2 = u0, u3 = u0;
  for (int c = 0; c < jc; ++c) {
    const float4* p = Upart + ((size_t)c * NPTS + i) * 4;
    add4(u0, p[0]); add4(u1, p[1]); add4(u2, p[2]); add4(u3, p[3]);
  }
  const float4 y0 = Yv[(size_t)i * 4 + 0];
  const float4 y1 = Yv[(size_t)i * 4 + 1];
  const float4 y2 = Yv[(size_t)i * 4 + 2];
  const float4 y3 = Yv[(size_t)i * 4 + 3];
  _Float16* dr = Dh + (size_t)i * DIM;
  dr[0]  = (_Float16)(u0.x - y0.x); dr[1]  = (_Float16)(u0.y - y0.y);
  dr[2]  = (_Float16)(u0.z - y0.z); dr[3]  = (_Float16)(u0.w - y0.w);
  dr[4]  = (_Float16)(u1.x - y1.x); dr[5]  = (_Float16)(u1.y - y1.y);
  dr[6]  = (_Float16)(u1.z - y1.z); dr[7]  = (_Float16)(u1.w - y1.w);
  dr[8]  = (_Float16)(u2.x - y2.x); dr[9]  = (_Float16)(u2.y - y2.y);
  dr[10] = (_Float16)(u2.z - y2.z); dr[11] = (_Float16)(u2.w - y2.w);
  dr[12] = (_Float16)(u3.x - y3.x); dr[13] = (_Float16)(u3.y - y3.y);
  dr[14] = (_Float16)(u3.z - y3.z); dr[15] = (_Float16)(u3.w - y3.w);

  const float4 l0 = Lv[(size_t)i * 4 + 0];
  const float4 l1 = Lv[(size_t)i * 4 + 1];
  const float4 l2 = Lv[(size_t)i * 4 + 2];
  const float4 l3 = Lv[(size_t)i * 4 + 3];
  const float regp = (dot4(l0, u0) + dot4(l1, u1)) + (dot4(l2, u2) + dot4(l3, u3));
  const float rtot = block_sum(regp, wred);
  if (threadIdx.x == 0) unsafeAtomicAdd(&accums[1], rtot);
}

// Pass 2: s += exp(mmd) * (diff_i . diff_j); two MFMA dots per tile, elementwise
// combine is lane-local (both C-frags share the C/D layout). 2 i-tiles per wave.
__global__ __launch_bounds__(BLK) void k_pass2(
    const _Float16* __restrict__ Xh, const _Float16* __restrict__ Dh,
    const float* __restrict__ csq2, float* __restrict__ accums, int span) {
  __shared__ float wred[BLK / 64];
  const int lane = threadIdx.x & 63;
  const int w    = threadIdx.x >> 6;
  const int l16  = lane & 15;
  const int quad = lane >> 4;
  const h8 hz = (h8)(_Float16)0.f;

  const int i0 = blockIdx.x * 128 + w * 32;  // tiles at i0 and i0+16
  h8 ax0 = hz, ax1 = hz, ad0 = hz, ad1 = hz;
  if (quad < 2) {
    ax0 = *(const h8*)(Xh + (size_t)(i0 + l16) * DIM + quad * 8);
    ax1 = *(const h8*)(Xh + (size_t)(i0 + 16 + l16) * DIM + quad * 8);
    ad0 = *(const h8*)(Dh + (size_t)(i0 + l16) * DIM + quad * 8);
    ad1 = *(const h8*)(Dh + (size_t)(i0 + 16 + l16) * DIM + quad * 8);
  }
  const int ir = i0 + quad * 4;
  f4 ci0, ci1;
#pragma unroll
  for (int r = 0; r < 4; ++r) { ci0[r] = csq2[ir + r]; ci1[r] = csq2[ir + 16 + r]; }

  float s = 0.f;
  const int jbeg = blockIdx.y * span;
  const int jend = jbeg + span;
  for (int j0 = jbeg; j0 < jend; j0 += 16) {
    h8 bx = hz, bd = hz;
    if (quad < 2) {
      bx = *(const h8*)(Xh + (size_t)(j0 + l16) * DIM + quad * 8);
      bd = *(const h8*)(Dh + (size_t)(j0 + l16) * DIM + quad * 8);
    }
    const float cj = csq2[j0 + l16];
    const f4 dx0 = __builtin_amdgcn_mfma_f32_16x16x32_f16(ax0, bx, (f4)0.f, 0, 0, 0);
    const f4 dd0 = __builtin_amdgcn_mfma_f32_16x16x32_f16(ad0, bd, (f4)0.f, 0, 0, 0);
    const f4 dx1 = __builtin_amdgcn_mfma_f32_16x16x32_f16(ax1, bx, (f4)0.f, 0, 0, 0);
    const f4 dd1 = __builtin_amdgcn_mfma_f32_16x16x32_f16(ad1, bd, (f4)0.f, 0, 0, 0);
#pragma unroll
    for (int r = 0; r < 4; ++r) {
      s = fmaf(__expf(fmaf(0.25f, dx0[r], ci0[r] + cj)), dd0[r], s);
      s = fmaf(__expf(fmaf(0.25f, dx1[r], ci1[r] + cj)), dd1[r], s);
    }
  }

  const float stot = block_sum(s, wred);
  if (threadIdx.x == 0) unsafeAtomicAdd(&accums[0], stot);
}

__global__ void k_final(const float* __restrict__ accums, float* __restrict__ out) {
  out[0] = accums[0] + REG_LAMBDA * accums[1];
}

extern "C" void kernel_launch(void* const* d_in, const int* in_sizes, int n_in,
                              void* d_out, int out_size, void* d_ws, size_t ws_size,
                              hipStream_t stream) {
  const float4* Xv = (const float4*)d_in[0];
  const float4* Yv = (const float4*)d_in[1];
  const float4* Lv = (const float4*)d_in[2];
  float* out = (float*)d_out;

  // ws layout (bytes): Xh 256K | LamT 256K | Dh 256K | csq1 32K | csq2 32K |
  //                    accums 256B | Upart jc*512K
  char* base = (char*)d_ws;
  _Float16* Xh   = (_Float16*)(base);
  _Float16* LamT = (_Float16*)(base + 256 * 1024);
  _Float16* Dh   = (_Float16*)(base + 512 * 1024);
  float*    csq1 = (float*)(base + 768 * 1024);
  float*    csq2 = (float*)(base + 800 * 1024);
  float*    accums = (float*)(base + 832 * 1024);
  float*    Upart  = (float*)(base + 832 * 1024 + 256);
  const size_t fixed = 832 * 1024 + 256;

  int jc = 8;
  while (jc > 1 && fixed + (size_t)jc * NPTS * DIM * 4 > ws_size) jc >>= 1;
  const int span1 = NPTS / jc;
  const int jc2 = 16, span2 = NPTS / jc2;

  hipMemsetAsync(accums, 0, 2 * sizeof(float), stream);
  k_prep<<<NIB, BLK, 0, stream>>>(Xv, Lv, Xh, LamT, csq1, csq2);
  k_pass1<<<dim3(NPTS / 64, jc), BLK, 0, stream>>>(Xh, LamT, csq1, Upart, span1);
  k_reduce<<<NIB, BLK, 0, stream>>>((const float4*)Upart, Yv, Lv, Dh, accums, jc);
  k_pass2<<<dim3(NPTS / 128, jc2), BLK, 0, stream>>>(Xh, Dh, csq2, accums, span2);
  k_final<<<1, 1, 0, stream>>>(accums, out);
}

// Round 7
// 120.595 us; speedup vs baseline: 6.1454x; 1.1220x over previous
//
#include <hip/hip_runtime.h>

// Problem: N=8192, D=16 RBF transport loss — all-MFMA, no-LDS formulation.
// Key trick: compute P^T via operand-swapped 16x16x16 MFMA; its C/D layout
// (row=j=quad*4+r, col=i=l16) is exactly the 16x16x16 A-operand layout
// (A[m=l16][k=quad*4+jj]) for the second MFMA U = P @ Lam. RBF bias folds
// into the MFMA C operand; exp() becomes raw v_exp_f32 via sqrt(log2e)
// pre-scaling of the fp16 X copies.
#define NPTS 8192
#define DIM  16

constexpr int BLK = 256;
constexpr int NIB = NPTS / BLK;   // 32

#define REG_LAMBDA 0.01f
// fit: exp(-d2/2) = exp2(-0.5*||c1(xi-xj)||^2), c1 = sqrt(log2e)
// mmd: exp(-d2/8) = exp2(-0.5*||c2(xi-xj)||^2), c2 = 0.5*sqrt(log2e)
#define C1 1.2011224087864498f
#define C2 0.6005612043932249f

typedef _Float16 h4 __attribute__((ext_vector_type(4)));
typedef float    f4 __attribute__((ext_vector_type(4)));

// Legacy K=16 MFMA builtin: no underscore before f16 (gfx950-new K=32 ones have it).
#define MFMA16(a, b, c) __builtin_amdgcn_mfma_f32_16x16x16f16((a), (b), (c), 0, 0, 0)

#if __has_builtin(__builtin_amdgcn_exp2f)
#define EXP2(x) __builtin_amdgcn_exp2f(x)
#else
#define EXP2(x) exp2f(x)
#endif

__device__ __forceinline__ float dot4(float4 a, float4 b) {
  return fmaf(a.x, b.x, fmaf(a.y, b.y, fmaf(a.z, b.z, a.w * b.w)));
}
__device__ __forceinline__ void add4(float4& a, float4 b) {
  a.x += b.x; a.y += b.y; a.z += b.z; a.w += b.w;
}

__device__ __forceinline__ float block_sum(float v, float* wbuf) {
#pragma unroll
  for (int o = 32; o > 0; o >>= 1) v += __shfl_down(v, o, 64);
  const int lane = threadIdx.x & 63;
  const int wid  = threadIdx.x >> 6;
  __syncthreads();
  if (lane == 0) wbuf[wid] = v;
  __syncthreads();
  float s = 0.f;
  if (threadIdx.x == 0) {
#pragma unroll
    for (int w = 0; w < BLK / 64; ++w) s += wbuf[w];
  }
  return s;
}

// Prep: two pre-scaled fp16 X copies (row-major), Lam transposed (16 x N),
// csq = -0.5*||scaled row||^2 computed from the ROUNDED values.
__global__ __launch_bounds__(BLK) void k_prep(
    const float4* __restrict__ Xv, const float4* __restrict__ Lv,
    _Float16* __restrict__ Xh1, _Float16* __restrict__ Xh2,
    _Float16* __restrict__ LamT,
    float* __restrict__ csq1, float* __restrict__ csq2) {
  const int i = blockIdx.x * BLK + threadIdx.x;
  float sq1 = 0.f, sq2 = 0.f;
  h4* x1 = (h4*)(Xh1 + (size_t)i * DIM);
  h4* x2 = (h4*)(Xh2 + (size_t)i * DIM);
#pragma unroll
  for (int q = 0; q < 4; ++q) {
    const float4 v = Xv[(size_t)i * 4 + q];
    h4 a = {(_Float16)(C1 * v.x), (_Float16)(C1 * v.y),
            (_Float16)(C1 * v.z), (_Float16)(C1 * v.w)};
    h4 b = {(_Float16)(C2 * v.x), (_Float16)(C2 * v.y),
            (_Float16)(C2 * v.z), (_Float16)(C2 * v.w)};
    x1[q] = a; x2[q] = b;
#pragma unroll
    for (int t = 0; t < 4; ++t) {
      const float fa = (float)a[t], fb = (float)b[t];
      sq1 = fmaf(fa, fa, sq1);
      sq2 = fmaf(fb, fb, sq2);
    }
    const float4 l = Lv[(size_t)i * 4 + q];
    LamT[(size_t)(4 * q + 0) * NPTS + i] = (_Float16)l.x;
    LamT[(size_t)(4 * q + 1) * NPTS + i] = (_Float16)l.y;
    LamT[(size_t)(4 * q + 2) * NPTS + i] = (_Float16)l.z;
    LamT[(size_t)(4 * q + 3) * NPTS + i] = (_Float16)l.w;
  }
  csq1[i] = -0.5f * sq1;
  csq2[i] = -0.5f * sq2;
}

// Pass 1: U = exp2(Xj.Xi^T + bias) @ Lam. Per wave: 2 i-tiles, no LDS.
__global__ __launch_bounds__(BLK) void k_pass1(
    const _Float16* __restrict__ Xh1, const _Float16* __restrict__ LamT,
    const float* __restrict__ csq1, float* __restrict__ Upart, int span) {
  const int lane = threadIdx.x & 63;
  const int w    = threadIdx.x >> 6;
  const int l16  = lane & 15;
  const int quad = lane >> 4;

  const int i0 = blockIdx.x * 128 + w * 32;   // tiles i0, i0+16
  const h4 bxi0 = *(const h4*)(Xh1 + (size_t)(i0 + l16) * DIM + quad * 4);
  const h4 bxi1 = *(const h4*)(Xh1 + (size_t)(i0 + 16 + l16) * DIM + quad * 4);
  const float ci0 = csq1[i0 + l16];
  const float ci1 = csq1[i0 + 16 + l16];
  const _Float16* blrow = LamT + (size_t)l16 * NPTS;

  f4 U0 = {0.f, 0.f, 0.f, 0.f}, U1 = U0;
  const int jbeg = blockIdx.y * span;
  const int jend = jbeg + span;
#pragma unroll 2
  for (int j0 = jbeg; j0 < jend; j0 += 16) {
    const h4 axj = *(const h4*)(Xh1 + (size_t)(j0 + l16) * DIM + quad * 4);
    const float4 cjf = *(const float4*)(csq1 + j0 + quad * 4);
    const f4 cc0 = {cjf.x + ci0, cjf.y + ci0, cjf.z + ci0, cjf.w + ci0};
    const f4 cc1 = {cjf.x + ci1, cjf.y + ci1, cjf.z + ci1, cjf.w + ci1};
    const f4 p0 = MFMA16(axj, bxi0, cc0);   // P^T tile 0 (+bias)
    const f4 p1 = MFMA16(axj, bxi1, cc1);   // P^T tile 1 (+bias)
    h4 ap0, ap1;
#pragma unroll
    for (int r = 0; r < 4; ++r) {
      ap0[r] = (_Float16)EXP2(p0[r]);
      ap1[r] = (_Float16)EXP2(p1[r]);
    }
    const h4 bl = *(const h4*)(blrow + j0 + quad * 4);
    U0 = MFMA16(ap0, bl, U0);
    U1 = MFMA16(ap1, bl, U1);
  }

  float* dst = Upart + ((size_t)blockIdx.y * NPTS + i0) * DIM;
#pragma unroll
  for (int r = 0; r < 4; ++r) {
    dst[(quad * 4 + r) * DIM + l16]        = U0[r];
    dst[(16 + quad * 4 + r) * DIM + l16]   = U1[r];
  }
}

// Reduce partials -> diff = U - Y (fp16 Dh); reg = sum(Lam * U).
// One thread per (i, quarter): 32768 threads.
__global__ __launch_bounds__(BLK) void k_reduce(
    const float4* __restrict__ Upart, const float4* __restrict__ Yv,
    const float4* __restrict__ Lv, _Float16* __restrict__ Dh,
    float* __restrict__ accums, int jc) {
  __shared__ float wred[BLK / 64];
  const int t = blockIdx.x * BLK + threadIdx.x;
  const int i = t >> 2, q = t & 3;
  float4 u = {0.f, 0.f, 0.f, 0.f};
  for (int c = 0; c < jc; ++c)
    add4(u, Upart[((size_t)c * NPTS + i) * 4 + q]);
  const float4 y = Yv[(size_t)i * 4 + q];
  h4 d = {(_Float16)(u.x - y.x), (_Float16)(u.y - y.y),
          (_Float16)(u.z - y.z), (_Float16)(u.w - y.w)};
  *(h4*)(Dh + (size_t)i * DIM + q * 4) = d;
  const float regp = dot4(Lv[(size_t)i * 4 + q], u);
  const float rtot = block_sum(regp, wred);
  if (threadIdx.x == 0) unsafeAtomicAdd(&accums[1], rtot);
}

// Pass 2: s += exp2(Xi.Xj^T + bias) * (diff_i . diff_j); lane-local combine.
__global__ __launch_bounds__(BLK) void k_pass2(
    const _Float16* __restrict__ Xh2, const _Float16* __restrict__ Dh,
    const float* __restrict__ csq2, float* __restrict__ accums, int span) {
  __shared__ float wred[BLK / 64];
  const int lane = threadIdx.x & 63;
  const int w    = threadIdx.x >> 6;
  const int l16  = lane & 15;
  const int quad = lane >> 4;
  const f4 fz = {0.f, 0.f, 0.f, 0.f};

  const int i0 = blockIdx.x * 128 + w * 32;   // tiles i0, i0+16
  const h4 ax0 = *(const h4*)(Xh2 + (size_t)(i0 + l16) * DIM + quad * 4);
  const h4 ax1 = *(const h4*)(Xh2 + (size_t)(i0 + 16 + l16) * DIM + quad * 4);
  const h4 ad0 = *(const h4*)(Dh  + (size_t)(i0 + l16) * DIM + quad * 4);
  const h4 ad1 = *(const h4*)(Dh  + (size_t)(i0 + 16 + l16) * DIM + quad * 4);
  const float4 cif0 = *(const float4*)(csq2 + i0 + quad * 4);
  const float4 cif1 = *(const float4*)(csq2 + i0 + 16 + quad * 4);

  float s = 0.f;
  const int jbeg = blockIdx.y * span;
  const int jend = jbeg + span;
#pragma unroll 2
  for (int j0 = jbeg; j0 < jend; j0 += 16) {
    const h4 bx = *(const h4*)(Xh2 + (size_t)(j0 + l16) * DIM + quad * 4);
    const h4 bd = *(const h4*)(Dh  + (size_t)(j0 + l16) * DIM + quad * 4);
    const float cj = csq2[j0 + l16];
    const f4 cc0 = {cif0.x + cj, cif0.y + cj, cif0.z + cj, cif0.w + cj};
    const f4 cc1 = {cif1.x + cj, cif1.y + cj, cif1.z + cj, cif1.w + cj};
    const f4 dx0 = MFMA16(ax0, bx, cc0);
    const f4 dd0 = MFMA16(ad0, bd, fz);
    const f4 dx1 = MFMA16(ax1, bx, cc1);
    const f4 dd1 = MFMA16(ad1, bd, fz);
#pragma unroll
    for (int r = 0; r < 4; ++r) {
      s = fmaf(EXP2(dx0[r]), dd0[r], s);
      s = fmaf(EXP2(dx1[r]), dd1[r], s);
    }
  }

  const float stot = block_sum(s, wred);
  if (threadIdx.x == 0) unsafeAtomicAdd(&accums[0], stot);
}

__global__ void k_final(const float* __restrict__ accums, float* __restrict__ out) {
  out[0] = accums[0] + REG_LAMBDA * accums[1];
}

extern "C" void kernel_launch(void* const* d_in, const int* in_sizes, int n_in,
                              void* d_out, int out_size, void* d_ws, size_t ws_size,
                              hipStream_t stream) {
  const float4* Xv = (const float4*)d_in[0];
  const float4* Yv = (const float4*)d_in[1];
  const float4* Lv = (const float4*)d_in[2];
  float* out = (float*)d_out;

  // ws layout (bytes): Xh1 256K | Xh2 256K | LamT 256K | Dh 256K |
  //                    csq1 32K | csq2 32K | accums 256B | Upart jc*512K
  char* base = (char*)d_ws;
  _Float16* Xh1  = (_Float16*)(base);
  _Float16* Xh2  = (_Float16*)(base + 256 * 1024);
  _Float16* LamT = (_Float16*)(base + 512 * 1024);
  _Float16* Dh   = (_Float16*)(base + 768 * 1024);
  float*    csq1 = (float*)(base + 1024 * 1024);
  float*    csq2 = (float*)(base + 1056 * 1024);
  float*    accums = (float*)(base + 1088 * 1024);
  float*    Upart  = (float*)(base + 1088 * 1024 + 256);
  const size_t fixed = 1088 * 1024 + 256;

  int jc = 16;
  while (jc > 1 && fixed + (size_t)jc * NPTS * DIM * 4 > ws_size) jc >>= 1;
  const int span1 = NPTS / jc;
  const int jc2 = 16, span2 = NPTS / jc2;

  hipMemsetAsync(accums, 0, 2 * sizeof(float), stream);
  k_prep<<<NIB, BLK, 0, stream>>>(Xv, Lv, Xh1, Xh2, LamT, csq1, csq2);
  k_pass1<<<dim3(NPTS / 128, jc), BLK, 0, stream>>>(Xh1, LamT, csq1, Upart, span1);
  k_reduce<<<NPTS * 4 / BLK, BLK, 0, stream>>>((const float4*)Upart, Yv, Lv, Dh, accums, jc);
  k_pass2<<<dim3(NPTS / 128, jc2), BLK, 0, stream>>>(Xh2, Dh, csq2, accums, span2);
  k_final<<<1, 1, 0, stream>>>(accums, out);
}

// Round 8
// 118.210 us; speedup vs baseline: 6.2694x; 1.0202x over previous
//
#include <hip/hip_runtime.h>

// N=8192, D=16 RBF transport loss — all-MFMA, no-LDS, 4 i-tiles per wave.
// P^T via operand-swapped 16x16x16 MFMA; C/D layout == A-operand layout, so
// exp(P^T) feeds the second MFMA directly (no LDS transpose). RBF bias rides
// in the MFMA C operand; exp() is raw v_exp_f32 via sqrt(log2e) pre-scaling.
#define NPTS 8192
#define DIM  16

constexpr int BLK = 256;
constexpr int NIB = NPTS / BLK;   // 32

#define REG_LAMBDA 0.01f
// fit: exp(-d2/2) = exp2(-0.5*||c1 x||...), c1 = sqrt(log2e)
// mmd: exp(-d2/8) -> c2 = 0.5*sqrt(log2e)
#define C1 1.2011224087864498f
#define C2 0.6005612043932249f

typedef _Float16 h4 __attribute__((ext_vector_type(4)));
typedef float    f4 __attribute__((ext_vector_type(4)));

// Legacy K=16 MFMA builtin spelling: no underscore before f16.
#define MFMA16(a, b, c) __builtin_amdgcn_mfma_f32_16x16x16f16((a), (b), (c), 0, 0, 0)

#if __has_builtin(__builtin_amdgcn_exp2f)
#define EXP2(x) __builtin_amdgcn_exp2f(x)
#else
#define EXP2(x) exp2f(x)
#endif

__device__ __forceinline__ float dot4(float4 a, float4 b) {
  return fmaf(a.x, b.x, fmaf(a.y, b.y, fmaf(a.z, b.z, a.w * b.w)));
}
__device__ __forceinline__ void add4(float4& a, float4 b) {
  a.x += b.x; a.y += b.y; a.z += b.z; a.w += b.w;
}

__device__ __forceinline__ float block_sum(float v, float* wbuf) {
#pragma unroll
  for (int o = 32; o > 0; o >>= 1) v += __shfl_down(v, o, 64);
  const int lane = threadIdx.x & 63;
  const int wid  = threadIdx.x >> 6;
  __syncthreads();
  if (lane == 0) wbuf[wid] = v;
  __syncthreads();
  float s = 0.f;
  if (threadIdx.x == 0) {
#pragma unroll
    for (int w = 0; w < BLK / 64; ++w) s += wbuf[w];
  }
  return s;
}

// Prep: two pre-scaled fp16 X copies, LamT (16 x N, fp16), csq from ROUNDED X.
__global__ __launch_bounds__(BLK) void k_prep(
    const float4* __restrict__ Xv, const float4* __restrict__ Lv,
    _Float16* __restrict__ Xh1, _Float16* __restrict__ Xh2,
    _Float16* __restrict__ LamT,
    float* __restrict__ csq1, float* __restrict__ csq2) {
  const int i = blockIdx.x * BLK + threadIdx.x;
  float sq1 = 0.f, sq2 = 0.f;
  h4* x1 = (h4*)(Xh1 + (size_t)i * DIM);
  h4* x2 = (h4*)(Xh2 + (size_t)i * DIM);
#pragma unroll
  for (int q = 0; q < 4; ++q) {
    const float4 v = Xv[(size_t)i * 4 + q];
    h4 a = {(_Float16)(C1 * v.x), (_Float16)(C1 * v.y),
            (_Float16)(C1 * v.z), (_Float16)(C1 * v.w)};
    h4 b = {(_Float16)(C2 * v.x), (_Float16)(C2 * v.y),
            (_Float16)(C2 * v.z), (_Float16)(C2 * v.w)};
    x1[q] = a; x2[q] = b;
#pragma unroll
    for (int t = 0; t < 4; ++t) {
      const float fa = (float)a[t], fb = (float)b[t];
      sq1 = fmaf(fa, fa, sq1);
      sq2 = fmaf(fb, fb, sq2);
    }
    const float4 l = Lv[(size_t)i * 4 + q];
    LamT[(size_t)(4 * q + 0) * NPTS + i] = (_Float16)l.x;
    LamT[(size_t)(4 * q + 1) * NPTS + i] = (_Float16)l.y;
    LamT[(size_t)(4 * q + 2) * NPTS + i] = (_Float16)l.z;
    LamT[(size_t)(4 * q + 3) * NPTS + i] = (_Float16)l.w;
  }
  csq1[i] = -0.5f * sq1;
  csq2[i] = -0.5f * sq2;
}

// Pass 1: U = exp2(Xj.Xi^T + bias) @ Lam. 4 i-tiles per wave, 256 i per block.
__global__ __launch_bounds__(BLK) void k_pass1(
    const _Float16* __restrict__ Xh1, const _Float16* __restrict__ LamT,
    const float* __restrict__ csq1, float* __restrict__ Upart, int span) {
  const int lane = threadIdx.x & 63;
  const int w    = threadIdx.x >> 6;
  const int l16  = lane & 15;
  const int quad = lane >> 4;

  const int i0 = blockIdx.x * 256 + w * 64;   // tiles i0+16t, t=0..3
  h4 bxi[4];
  float ci[4];
#pragma unroll
  for (int t = 0; t < 4; ++t) {
    bxi[t] = *(const h4*)(Xh1 + (size_t)(i0 + 16 * t + l16) * DIM + quad * 4);
    ci[t]  = csq1[i0 + 16 * t + l16];
  }
  const _Float16* blrow = LamT + (size_t)l16 * NPTS;

  f4 U[4] = {{0.f, 0.f, 0.f, 0.f}, {0.f, 0.f, 0.f, 0.f},
             {0.f, 0.f, 0.f, 0.f}, {0.f, 0.f, 0.f, 0.f}};
  const int jbeg = blockIdx.y * span;
  const int jend = jbeg + span;
#pragma unroll 2
  for (int j0 = jbeg; j0 < jend; j0 += 16) {
    const h4 axj = *(const h4*)(Xh1 + (size_t)(j0 + l16) * DIM + quad * 4);
    const float4 cjf = *(const float4*)(csq1 + j0 + quad * 4);
    const h4 bl = *(const h4*)(blrow + j0 + quad * 4);
#pragma unroll
    for (int t = 0; t < 4; ++t) {
      const f4 cc = {cjf.x + ci[t], cjf.y + ci[t], cjf.z + ci[t], cjf.w + ci[t]};
      const f4 p = MFMA16(axj, bxi[t], cc);   // P^T tile t (+bias)
      h4 ap;
#pragma unroll
      for (int r = 0; r < 4; ++r) ap[r] = (_Float16)EXP2(p[r]);
      U[t] = MFMA16(ap, bl, U[t]);
    }
  }

  float* dst = Upart + ((size_t)blockIdx.y * NPTS + i0) * DIM;
#pragma unroll
  for (int t = 0; t < 4; ++t)
#pragma unroll
    for (int r = 0; r < 4; ++r)
      dst[(16 * t + quad * 4 + r) * DIM + l16] = U[t][r];
}

// Reduce partials -> diff = U - Y (fp16 Dh); reg = sum(Lam * U).
__global__ __launch_bounds__(BLK) void k_reduce(
    const float4* __restrict__ Upart, const float4* __restrict__ Yv,
    const float4* __restrict__ Lv, _Float16* __restrict__ Dh,
    float* __restrict__ accums, int jc) {
  __shared__ float wred[BLK / 64];
  const int t = blockIdx.x * BLK + threadIdx.x;
  const int i = t >> 2, q = t & 3;
  float4 u = {0.f, 0.f, 0.f, 0.f};
  for (int c = 0; c < jc; ++c)
    add4(u, Upart[((size_t)c * NPTS + i) * 4 + q]);
  const float4 y = Yv[(size_t)i * 4 + q];
  h4 d = {(_Float16)(u.x - y.x), (_Float16)(u.y - y.y),
          (_Float16)(u.z - y.z), (_Float16)(u.w - y.w)};
  *(h4*)(Dh + (size_t)i * DIM + q * 4) = d;
  const float regp = dot4(Lv[(size_t)i * 4 + q], u);
  const float rtot = block_sum(regp, wred);
  if (threadIdx.x == 0) unsafeAtomicAdd(&accums[1], rtot);
}

// Pass 2: s += exp2(Xi.Xj^T + bias) * (diff_i . diff_j); 4 i-tiles per wave.
__global__ __launch_bounds__(BLK) void k_pass2(
    const _Float16* __restrict__ Xh2, const _Float16* __restrict__ Dh,
    const float* __restrict__ csq2, float* __restrict__ accums, int span) {
  __shared__ float wred[BLK / 64];
  const int lane = threadIdx.x & 63;
  const int w    = threadIdx.x >> 6;
  const int l16  = lane & 15;
  const int quad = lane >> 4;
  const f4 fz = {0.f, 0.f, 0.f, 0.f};

  const int i0 = blockIdx.x * 256 + w * 64;
  h4 ax[4], ad[4];
  float4 cif[4];
#pragma unroll
  for (int t = 0; t < 4; ++t) {
    ax[t] = *(const h4*)(Xh2 + (size_t)(i0 + 16 * t + l16) * DIM + quad * 4);
    ad[t] = *(const h4*)(Dh  + (size_t)(i0 + 16 * t + l16) * DIM + quad * 4);
    cif[t] = *(const float4*)(csq2 + i0 + 16 * t + quad * 4);
  }

  float s = 0.f;
  const int jbeg = blockIdx.y * span;
  const int jend = jbeg + span;
#pragma unroll 2
  for (int j0 = jbeg; j0 < jend; j0 += 16) {
    const h4 bx = *(const h4*)(Xh2 + (size_t)(j0 + l16) * DIM + quad * 4);
    const h4 bd = *(const h4*)(Dh  + (size_t)(j0 + l16) * DIM + quad * 4);
    const float cj = csq2[j0 + l16];
#pragma unroll
    for (int t = 0; t < 4; ++t) {
      const f4 cc = {cif[t].x + cj, cif[t].y + cj, cif[t].z + cj, cif[t].w + cj};
      const f4 dx = MFMA16(ax[t], bx, cc);
      const f4 dd = MFMA16(ad[t], bd, fz);
#pragma unroll
      for (int r = 0; r < 4; ++r) s = fmaf(EXP2(dx[r]), dd[r], s);
    }
  }

  const float stot = block_sum(s, wred);
  if (threadIdx.x == 0) unsafeAtomicAdd(&accums[0], stot);
}

__global__ void k_final(const float* __restrict__ accums, float* __restrict__ out) {
  out[0] = accums[0] + REG_LAMBDA * accums[1];
}

extern "C" void kernel_launch(void* const* d_in, const int* in_sizes, int n_in,
                              void* d_out, int out_size, void* d_ws, size_t ws_size,
                              hipStream_t stream) {
  const float4* Xv = (const float4*)d_in[0];
  const float4* Yv = (const float4*)d_in[1];
  const float4* Lv = (const float4*)d_in[2];
  float* out = (float*)d_out;

  // ws layout (bytes): Xh1 256K | Xh2 256K | LamT 256K | Dh 256K |
  //                    csq1 32K | csq2 32K | accums 256B | Upart jc*512K
  char* base = (char*)d_ws;
  _Float16* Xh1  = (_Float16*)(base);
  _Float16* Xh2  = (_Float16*)(base + 256 * 1024);
  _Float16* LamT = (_Float16*)(base + 512 * 1024);
  _Float16* Dh   = (_Float16*)(base + 768 * 1024);
  float*    csq1 = (float*)(base + 1024 * 1024);
  float*    csq2 = (float*)(base + 1056 * 1024);
  float*    accums = (float*)(base + 1088 * 1024);
  float*    Upart  = (float*)(base + 1088 * 1024 + 256);
  const size_t fixed = 1088 * 1024 + 256;

  int jc = 32;
  while (jc > 1 && fixed + (size_t)jc * NPTS * DIM * 4 > ws_size) jc >>= 1;
  const int span1 = NPTS / jc;
  const int jc2 = 32, span2 = NPTS / jc2;

  hipMemsetAsync(accums, 0, 2 * sizeof(float), stream);
  k_prep<<<NIB, BLK, 0, stream>>>(Xv, Lv, Xh1, Xh2, LamT, csq1, csq2);
  k_pass1<<<dim3(NPTS / 256, jc), BLK, 0, stream>>>(Xh1, LamT, csq1, Upart, span1);
  k_reduce<<<NPTS * 4 / BLK, BLK, 0, stream>>>((const float4*)Upart, Yv, Lv, Dh, accums, jc);
  k_pass2<<<dim3(NPTS / 256, jc2), BLK, 0, stream>>>(Xh2, Dh, csq2, accums, span2);
  k_final<<<1, 1, 0, stream>>>(accums, out);
}